// Round 3
// baseline (614.060 us; speedup 1.0000x reference)
//
#include <hip/hip_runtime.h>

// SpaAggregator: out[b] = (mean_k id2feat[idx[b,k]]) @ W + bias
// B=16384, K=32, N=1e6, F=128, E=128. float32 in/out, int32 indices.
//
// mean commutes with the linear map: gather-average first (256 MB random
// 512B-row reads, memory-bound), then a tiny per-row GEMM with W read
// straight from global (64 KB, L1/L2-resident -> no LDS staging, so
// occupancy is ~6 blocks/CU instead of 2).
//
// Block = 256 threads handles 8 batch rows (grid 2048):
//   phase 1: stage 8x32 neighbor indices in LDS
//   phase 2: gather-average; 32 lanes x 16B cover one 512B table row
//            contiguously (each wave-load = two perfect 512B segments)
//   phase 3: thread (lr, c) computes out[b0+lr][c*4 .. c*4+4) from
//            sA (LDS, padded) and W rows (global, cache-hit).

#define BATCH 16384
#define KNB   32
#define FDIM  128
#define EDIM  128
#define ROWS_PER_BLOCK 8
#define IDX_PITCH 33   // pad so per-row idx streams start on different banks
#define A_PITCH  132   // pad kills power-of-2 conflicts on phase-3 broadcasts

__global__ __launch_bounds__(256, 6)
void spa_agg_kernel(const float* __restrict__ id2feat,
                    const float* __restrict__ weight,
                    const float* __restrict__ bias,
                    const int* __restrict__ neigh_idx,
                    float* __restrict__ out) {
    __shared__ float sA[ROWS_PER_BLOCK * A_PITCH];     // ~4.2 KB
    __shared__ int   sIdx[ROWS_PER_BLOCK * IDX_PITCH]; // ~1.1 KB

    const int tid = threadIdx.x;
    const int lr  = tid >> 5;   // 0..7  : local batch row
    const int c   = tid & 31;   // 0..31 : 4-wide feature/embed chunk
    const int b0  = blockIdx.x * ROWS_PER_BLOCK;

    // ---- phase 1: stage neighbor indices (one per thread, coalesced) ----
    {
        const int i = tid;                       // 8*32 == 256 == blockDim
        sIdx[(i >> 5) * IDX_PITCH + (i & 31)] = neigh_idx[b0 * KNB + i];
    }
    __syncthreads();

    // ---- phase 2: gather + average ----
    // thread (lr, c) accumulates features [c*4, c*4+4) of local row lr.
    // 32 consecutive lanes read one 512B table row contiguously (16B/lane).
    {
        float4 acc = make_float4(0.f, 0.f, 0.f, 0.f);
        const int* ip = &sIdx[lr * IDX_PITCH];
        #pragma unroll 8
        for (int k = 0; k < KNB; ++k) {
            const int row = ip[k];
            const float4 r = *(const float4*)(id2feat + (size_t)row * FDIM + c * 4);
            acc.x += r.x; acc.y += r.y; acc.z += r.z; acc.w += r.w;
        }
        float* ap = &sA[lr * A_PITCH + c * 4];
        ap[0] = acc.x * (1.f / 32.f);
        ap[1] = acc.y * (1.f / 32.f);
        ap[2] = acc.z * (1.f / 32.f);
        ap[3] = acc.w * (1.f / 32.f);
    }
    __syncthreads();

    // ---- phase 3: out[b0+lr][e0..e0+4) = sA[lr] . W[:, e0..e0+4) + bias ----
    // W rows read from global: 32 lanes x 16B = contiguous 512B per f,
    // L1/L2-hit after first touch (W is only 64 KB).
    {
        const int e0 = c * 4;
        float4 acc = *(const float4*)(bias + e0);
        const float* arow = &sA[lr * A_PITCH];
        #pragma unroll 4
        for (int f = 0; f < FDIM; ++f) {
            const float  a = arow[f];  // LDS broadcast, distinct banks per lr
            const float4 w = *(const float4*)(weight + (size_t)f * EDIM + e0);
            acc.x += a * w.x; acc.y += a * w.y;
            acc.z += a * w.z; acc.w += a * w.w;
        }
        *(float4*)(out + (size_t)(b0 + lr) * EDIM + e0) = acc;
    }
}

extern "C" void kernel_launch(void* const* d_in, const int* in_sizes, int n_in,
                              void* d_out, int out_size, void* d_ws, size_t ws_size,
                              hipStream_t stream) {
    const float* id2feat = (const float*)d_in[0];  // [N, F] fp32
    const float* weight  = (const float*)d_in[1];  // [F, E] fp32
    const float* bias    = (const float*)d_in[2];  // [E]    fp32
    const int*   neigh   = (const int*)d_in[3];    // [B, K] int32
    float*       outp    = (float*)d_out;          // [B, E] fp32

    dim3 grid(BATCH / ROWS_PER_BLOCK);  // 2048
    dim3 block(256);
    spa_agg_kernel<<<grid, block, 0, stream>>>(id2feat, weight, bias, neigh, outp);
}